// Round 1
// baseline (1396.233 us; speedup 1.0000x reference)
//
#include <hip/hip_runtime.h>
#include <stdint.h>

#define NC 5
#define IMAXP1 33
#define SEGS (NC * IMAXP1)      // 165
#define HW_ (512 * 512)
#define IGNORE_L 255
#define CHUNK 65536             // pixels per segsum block

// ---------------- Pass 1: seg ids + counts ----------------
__global__ __launch_bounds__(256) void seg_count_kernel(
    const int* __restrict__ labels, const int* __restrict__ indexes,
    uint8_t* __restrict__ seg, unsigned* __restrict__ counts,
    int pix_per_block) {
  __shared__ unsigned hist[SEGS];
  for (int i = threadIdx.x; i < SEGS; i += blockDim.x) hist[i] = 0u;
  __syncthreads();

  const long long base = (long long)blockIdx.x * pix_per_block;
  const int b = (int)(base / HW_);          // pix_per_block divides HW_
  const int nvec = pix_per_block / 4;
  const int4* lab4 = (const int4*)(labels + base);
  const int4* idx4 = (const int4*)(indexes + base);
  uchar4* seg4 = (uchar4*)(seg + base);

  for (int k = threadIdx.x; k < nvec; k += blockDim.x) {
    int4 l = lab4[k];
    int4 ix = idx4[k];
    int s0 = (l.x == IGNORE_L) ? 0 : l.x * IMAXP1 + ix.x;
    int s1 = (l.y == IGNORE_L) ? 0 : l.y * IMAXP1 + ix.y;
    int s2 = (l.z == IGNORE_L) ? 0 : l.z * IMAXP1 + ix.z;
    int s3 = (l.w == IGNORE_L) ? 0 : l.w * IMAXP1 + ix.w;
    uchar4 sv;
    sv.x = (unsigned char)s0; sv.y = (unsigned char)s1;
    sv.z = (unsigned char)s2; sv.w = (unsigned char)s3;
    seg4[k] = sv;
    atomicAdd(&hist[s0], 1u);
    atomicAdd(&hist[s1], 1u);
    atomicAdd(&hist[s2], 1u);
    atomicAdd(&hist[s3], 1u);
  }
  __syncthreads();
  for (int i = threadIdx.x; i < SEGS; i += blockDim.x)
    if (hist[i]) atomicAdd(&counts[b * SEGS + i], hist[i]);
}

// ---------------- Pass 2: segment sums of the feature tensor ----------------
// One block per (b, d, pixel-chunk). Streams the contiguous (b,d) plane chunk
// with float4 loads; scatter-adds into per-wave-private LDS histograms.
__global__ __launch_bounds__(256) void segsum_kernel(
    const float* __restrict__ feat, const uint8_t* __restrict__ seg,
    float* __restrict__ sums, int D, int chunks_per_plane) {
  __shared__ float hist[4 * SEGS];
  const int bid = blockIdx.x;
  const int chunk = bid % chunks_per_plane;
  const int bd = bid / chunks_per_plane;
  const int d = bd % D;
  const int b = bd / D;

  for (int i = threadIdx.x; i < 4 * SEGS; i += 256) hist[i] = 0.f;
  __syncthreads();

  const int woff = (threadIdx.x >> 6) * SEGS;
  const float4* f4 =
      (const float4*)(feat + (size_t)(b * D + d) * HW_ + (size_t)chunk * CHUNK);
  const uchar4* s4 =
      (const uchar4*)(seg + (size_t)b * HW_ + (size_t)chunk * CHUNK);

  #pragma unroll 4
  for (int k = threadIdx.x; k < CHUNK / 4; k += 256) {
    float4 v = f4[k];
    uchar4 sv = s4[k];
    atomicAdd(&hist[woff + sv.x], v.x);
    atomicAdd(&hist[woff + sv.y], v.y);
    atomicAdd(&hist[woff + sv.z], v.z);
    atomicAdd(&hist[woff + sv.w], v.w);
  }
  __syncthreads();

  if (threadIdx.x < SEGS) {
    float t = hist[threadIdx.x] + hist[SEGS + threadIdx.x] +
              hist[2 * SEGS + threadIdx.x] + hist[3 * SEGS + threadIdx.x];
    if (t != 0.f)
      atomicAdd(&sums[((size_t)b * SEGS + threadIdx.x) * D + d], t);
  }
}

// ---------------- Pass 3: per-(image,class) pairwise loss ----------------
__global__ __launch_bounds__(256) void pairloss_kernel(
    const float* __restrict__ sums, const unsigned* __restrict__ counts,
    float* __restrict__ loss_sum, unsigned* __restrict__ nvalid, int D) {
  const int b = blockIdx.x / NC;
  const int c = blockIdx.x % NC;

  __shared__ float sh_mean[32 * 128];
  __shared__ float sh_cnt[IMAXP1];
  __shared__ int list[IMAXP1];
  __shared__ int Ksh;
  __shared__ uchar2 pairs[32 * 31 / 2];
  __shared__ double wred[4];

  if (threadIdx.x == 0) {
    int K = 0;
    for (int i = 1; i < IMAXP1; ++i) {   // slot 0 (ignore key) excluded
      unsigned cnt = counts[b * SEGS + c * IMAXP1 + i];
      if (cnt >= 2u) {                   // singleton segments excluded
        list[K] = i;
        sh_cnt[K] = (float)cnt;
        ++K;
      }
    }
    Ksh = K;
    int p = 0;
    for (int i = 0; i < K; ++i)
      for (int j = i + 1; j < K; ++j) {
        pairs[p].x = (unsigned char)i;
        pairs[p].y = (unsigned char)j;
        ++p;
      }
  }
  __syncthreads();
  const int K = Ksh;
  if (K == 0) return;                    // has=0 for this (b,c)

  // stage means of included instances in LDS
  for (int idx = threadIdx.x; idx < K * D; idx += blockDim.x) {
    int k = idx / 128, d = idx % 128;    // D==128
    int s = c * IMAXP1 + list[k];
    sh_mean[k * 128 + d] =
        sums[((size_t)b * SEGS + s) * D + d] / sh_cnt[k];
  }
  __syncthreads();

  const int npairs = K * (K - 1) / 2;
  const int total = npairs * 128;
  float local = 0.f;
  for (int idx = threadIdx.x; idx < total; idx += blockDim.x) {
    int p = idx >> 7, d = idx & 127;
    int i = pairs[p].x, j = pairs[p].y;
    local += fabsf(sh_mean[i * 128 + d] - sh_mean[j * 128 + d]);
  }

  double v = (double)local;
  #pragma unroll
  for (int off = 32; off; off >>= 1) v += __shfl_down(v, off, 64);
  const int wave = threadIdx.x >> 6;
  if ((threadIdx.x & 63) == 0) wred[wave] = v;
  __syncthreads();
  if (threadIdx.x == 0) {
    double ssum = 2.0 * (wred[0] + wred[1] + wred[2] + wred[3]);
    double ret = ssum / ((double)K * (double)K * (double)D);
    double loss = (ret < 1.0) ? 0.5 * ret * ret : ret - 0.5;
    atomicAdd(loss_sum, (float)loss);
    atomicAdd(nvalid, 1u);
  }
}

// ---------------- Pass 4: finalize ----------------
__global__ void finalize_kernel(const float* __restrict__ loss_sum,
                                const unsigned* __restrict__ nvalid,
                                float* __restrict__ out, int B) {
  if (threadIdx.x == 0) {
    unsigned n = *nvalid;
    out[0] = n ? (*loss_sum / (float)n) / (float)B : 0.f;
  }
}

extern "C" void kernel_launch(void* const* d_in, const int* in_sizes, int n_in,
                              void* d_out, int out_size, void* d_ws,
                              size_t ws_size, hipStream_t stream) {
  const float* feat = (const float*)d_in[0];
  const int* labels = (const int*)d_in[1];
  const int* indexes = (const int*)d_in[2];

  const int npix_total = in_sizes[1];          // B*H*W
  const int B = npix_total / HW_;              // 8
  const int D = in_sizes[0] / npix_total;      // 128

  // workspace layout: [seg bytes][sums f32][counts u32][loss f32][n u32]
  uint8_t* seg = (uint8_t*)d_ws;
  size_t off = ((size_t)npix_total + 255) & ~(size_t)255;
  float* sums = (float*)((char*)d_ws + off);
  size_t sums_bytes = (size_t)B * SEGS * D * sizeof(float);
  unsigned* counts = (unsigned*)((char*)d_ws + off + sums_bytes);
  size_t counts_bytes = (size_t)B * SEGS * sizeof(unsigned);
  float* loss_sum = (float*)((char*)d_ws + off + sums_bytes + counts_bytes);
  unsigned* nvalid = (unsigned*)(loss_sum + 1);

  // zero the accumulator region (sums..nvalid) every call
  hipMemsetAsync(sums, 0, sums_bytes + counts_bytes + 2 * sizeof(unsigned),
                 stream);

  const int pix_per_block = 4096;              // divides HW_
  seg_count_kernel<<<npix_total / pix_per_block, 256, 0, stream>>>(
      labels, indexes, seg, counts, pix_per_block);

  const int cpp = HW_ / CHUNK;                 // 4 chunks per plane
  segsum_kernel<<<B * D * cpp, 256, 0, stream>>>(feat, seg, sums, D, cpp);

  pairloss_kernel<<<B * NC, 256, 0, stream>>>(sums, counts, loss_sum, nvalid,
                                              D);
  finalize_kernel<<<1, 64, 0, stream>>>(loss_sum, nvalid, (float*)d_out, B);
}